// Round 1
// baseline (722.179 us; speedup 1.0000x reference)
//
#include <hip/hip_runtime.h>
#include <cstddef>

// Problem constants (fixed by the reference)
constexpr int Bn   = 8192;
constexpr int INn  = 512;
constexpr int EMBn = 512;
constexpr int HIDn = 1024;
constexpr int HYPn = 256;
constexpr int NZn  = 64;
constexpr float EPS = 1e-5f;

// ---------------------------------------------------------------------------
// Shared NT-GEMM tile accumulator: C[64x64] += A[M,K] @ B[N,K]^T
// A row-major (lda), B row-major (ldb) with K as the fast (contracted) dim.
// 256 threads, BK=16, 4x4 micro-tile per thread. LDS tiles stored K-major
// with pad 68 (272 B row stride -> 16B-aligned float4 reads, ~2-way banks).
// ---------------------------------------------------------------------------
__device__ __forceinline__ void nt_accum(
    const float* __restrict__ A, const float* __restrict__ Bm,
    int K, int lda, int ldb, int row0, int col0, int t,
    float acc[4][4], float* As, float* Bs)
{
    const int lr = t >> 2;          // 0..63 : tile row loaded by this thread
    const int lk = (t & 3) << 2;    // 0,4,8,12 : k-offset of its float4
    const int ty = t >> 4;          // 0..15 : 4 output rows
    const int tx = t & 15;          // 0..15 : 4 output cols

    for (int k0 = 0; k0 < K; k0 += 16) {
        const float4 av = *(const float4*)(A  + (size_t)(row0 + lr) * lda + k0 + lk);
        const float4 bv = *(const float4*)(Bm + (size_t)(col0 + lr) * ldb + k0 + lk);
        __syncthreads();            // protect previous iteration's LDS reads
        As[(lk + 0) * 68 + lr] = av.x;
        As[(lk + 1) * 68 + lr] = av.y;
        As[(lk + 2) * 68 + lr] = av.z;
        As[(lk + 3) * 68 + lr] = av.w;
        Bs[(lk + 0) * 68 + lr] = bv.x;
        Bs[(lk + 1) * 68 + lr] = bv.y;
        Bs[(lk + 2) * 68 + lr] = bv.z;
        Bs[(lk + 3) * 68 + lr] = bv.w;
        __syncthreads();
#pragma unroll
        for (int kk = 0; kk < 16; ++kk) {
            const float4 a = *(const float4*)(As + kk * 68 + ty * 4);
            const float4 b = *(const float4*)(Bs + kk * 68 + tx * 4);
            const float ar[4] = {a.x, a.y, a.z, a.w};
            const float br[4] = {b.x, b.y, b.z, b.w};
#pragma unroll
            for (int i = 0; i < 4; ++i)
#pragma unroll
                for (int j = 0; j < 4; ++j)
                    acc[i][j] = fmaf(ar[i], br[j], acc[i][j]);
        }
    }
}

// ---------------------------------------------------------------------------
// Kernel A: ifgo[8192,1024] = e @ Wx^T + h_hat @ Wh^T + b
// ---------------------------------------------------------------------------
__global__ __launch_bounds__(256) void k_ifgo(
    const float* __restrict__ e, const float* __restrict__ hhat,
    const float* __restrict__ Wx, const float* __restrict__ Wh,
    const float* __restrict__ bias, float* __restrict__ ifgo)
{
    __shared__ float As[16 * 68];
    __shared__ float Bs[16 * 68];
    float acc[4][4] = {};
    const int row0 = blockIdx.x * 64;
    const int col0 = blockIdx.y * 64;
    const int t = threadIdx.x;

    nt_accum(e,    Wx, EMBn, EMBn, EMBn, row0, col0, t, acc, As, Bs);
    nt_accum(hhat, Wh, HYPn, HYPn, HYPn, row0, col0, t, acc, As, Bs);

    const int ty = t >> 4, tx = t & 15;
    const float4 bv = *(const float4*)(bias + col0 + tx * 4);
#pragma unroll
    for (int i = 0; i < 4; ++i) {
        float4 o;
        o.x = acc[i][0] + bv.x; o.y = acc[i][1] + bv.y;
        o.z = acc[i][2] + bv.z; o.w = acc[i][3] + bv.w;
        *(float4*)(ifgo + (size_t)(row0 + ty * 4 + i) * (4 * HYPn) + col0 + tx * 4) = o;
    }
}

// ---------------------------------------------------------------------------
// Kernel B: per-row hyper cell.  One block (256 thr = 4 waves) per row.
// Wave g handles gate g's LN (256 elems, 4/lane), then all 256 threads do
// the c_hat_n / h_hat_n elementwise + block LN over 256.
// ---------------------------------------------------------------------------
__global__ __launch_bounds__(256) void k_cell(
    const float* __restrict__ ifgo, const float* __restrict__ c_hat,
    const float* __restrict__ ln_g, const float* __restrict__ ln_b,
    const float* __restrict__ lnc_g, const float* __restrict__ lnc_b,
    float* __restrict__ h_hat_n)
{
    const int row = blockIdx.x;
    const int t = threadIdx.x;
    const int lane = t & 63;
    const int wid = t >> 6;          // == gate index for the load below

    __shared__ float act[4][256];
    __shared__ float red[8];

    // thread t's float4 at offset 4t lies entirely inside gate (t>>6)
    const float4 v = *(const float4*)(ifgo + (size_t)row * 1024 + t * 4);
    float s  = v.x + v.y + v.z + v.w;
    float ss = v.x * v.x + v.y * v.y + v.z * v.z + v.w * v.w;
#pragma unroll
    for (int off = 32; off > 0; off >>= 1) {
        s  += __shfl_xor(s, off);
        ss += __shfl_xor(ss, off);
    }
    const float m    = s * (1.f / 256.f);
    const float var  = fmaxf(ss * (1.f / 256.f) - m * m, 0.f);
    const float rstd = rsqrtf(var + EPS);

    const int jb = lane * 4;  // index within gate
    const float4 g4 = *(const float4*)(ln_g + wid * 256 + jb);
    const float4 b4 = *(const float4*)(ln_b + wid * 256 + jb);
    float y[4];
    y[0] = (v.x - m) * rstd * g4.x + b4.x;
    y[1] = (v.y - m) * rstd * g4.y + b4.y;
    y[2] = (v.z - m) * rstd * g4.z + b4.z;
    y[3] = (v.w - m) * rstd * g4.w + b4.w;
#pragma unroll
    for (int k = 0; k < 4; ++k) {
        float a;
        if (wid == 2) a = tanhf(y[k]);               // g gate
        else          a = 1.f / (1.f + expf(-y[k])); // i, f, o gates
        act[wid][jb + k] = a;
    }
    __syncthreads();

    // phase 2: j = t  (0..255)
    const float si = act[0][t];
    const float sf = act[1][t];
    const float tg = act[2][t];
    const float so = act[3][t];
    const float cn = sf * c_hat[(size_t)row * 256 + t] + si * tg;

    float s2 = cn, ss2 = cn * cn;
#pragma unroll
    for (int off = 32; off > 0; off >>= 1) {
        s2  += __shfl_xor(s2, off);
        ss2 += __shfl_xor(ss2, off);
    }
    if (lane == 0) { red[wid] = s2; red[4 + wid] = ss2; }
    __syncthreads();
    const float tot  = red[0] + red[1] + red[2] + red[3];
    const float tots = red[4] + red[5] + red[6] + red[7];
    const float m2   = tot * (1.f / 256.f);
    const float var2 = fmaxf(tots * (1.f / 256.f) - m2 * m2, 0.f);
    const float r2   = rsqrtf(var2 + EPS);
    const float hn   = so * tanhf((cn - m2) * r2 * lnc_g[t] + lnc_b[t]);
    h_hat_n[(size_t)row * 256 + t] = hn;
}

// ---------------------------------------------------------------------------
// Kernel C: z = h_hat_n @ W^T (+ bias).  mode 0: row-major store [B,256].
// mode 1: z_b -> out3 laid out as [4, B, 64] (the transpose(1,0,2)).
// ---------------------------------------------------------------------------
__global__ __launch_bounds__(256) void k_z(
    const float* __restrict__ hn, const float* __restrict__ W,
    const float* __restrict__ bias, float* __restrict__ out, int mode)
{
    __shared__ float As[16 * 68];
    __shared__ float Bs[16 * 68];
    float acc[4][4] = {};
    const int row0 = blockIdx.x * 64;
    const int col0 = blockIdx.y * 64;
    const int t = threadIdx.x;

    nt_accum(hn, W, HYPn, HYPn, HYPn, row0, col0, t, acc, As, Bs);

    const int ty = t >> 4, tx = t & 15;
    if (mode == 0) {
        const float4 bv = *(const float4*)(bias + col0 + tx * 4);
#pragma unroll
        for (int i = 0; i < 4; ++i) {
            float4 o;
            o.x = acc[i][0] + bv.x; o.y = acc[i][1] + bv.y;
            o.z = acc[i][2] + bv.z; o.w = acc[i][3] + bv.w;
            *(float4*)(out + (size_t)(row0 + ty * 4 + i) * 256 + col0 + tx * 4) = o;
        }
    } else {
        // col0 is a multiple of 64 -> whole tile belongs to gate g = col0>>6
        const int g = col0 >> 6;
#pragma unroll
        for (int i = 0; i < 4; ++i) {
            float4 o;
            o.x = acc[i][0]; o.y = acc[i][1]; o.z = acc[i][2]; o.w = acc[i][3];
            *(float4*)(out + ((size_t)g * Bn + row0 + ty * 4 + i) * 64 + tx * 4) = o;
        }
    }
}

// ---------------------------------------------------------------------------
// Kernel D (precompute): M[g] = dW[g]^T @ w[g]   ([NZ=64, N]), contraction
// over h = 1024 (the slow dim of both row-major operands -> TN GEMM).
// One block: full 64 z-rows x 64 n-cols, BK=32.
// ---------------------------------------------------------------------------
__global__ __launch_bounds__(256) void k_dm(
    const float* __restrict__ dW, const float* __restrict__ w,
    float* __restrict__ M, int N)
{
    const int g = blockIdx.z;
    const float* A  = dW + (size_t)g * HIDn * NZn;  // [1024, 64]
    const float* Bw = w  + (size_t)g * HIDn * N;    // [1024, N]
    float* Mg = M + (size_t)g * NZn * N;
    const int col0 = blockIdx.x * 64;
    const int t = threadIdx.x;

    __shared__ float As[32 * 68];
    __shared__ float Bs[32 * 68];
    float acc[4][4] = {};
    const int lh = t >> 4;          // 0..15
    const int lc = (t & 15) * 4;    // 0..60
    const int ty = t >> 4, tx = t & 15;

    for (int h0 = 0; h0 < HIDn; h0 += 32) {
        const float4 a0 = *(const float4*)(A  + (size_t)(h0 + lh)      * NZn + lc);
        const float4 a1 = *(const float4*)(A  + (size_t)(h0 + 16 + lh) * NZn + lc);
        const float4 b0 = *(const float4*)(Bw + (size_t)(h0 + lh)      * N + col0 + lc);
        const float4 b1 = *(const float4*)(Bw + (size_t)(h0 + 16 + lh) * N + col0 + lc);
        __syncthreads();
        *(float4*)(As + lh * 68 + lc)        = a0;
        *(float4*)(As + (16 + lh) * 68 + lc) = a1;
        *(float4*)(Bs + lh * 68 + lc)        = b0;
        *(float4*)(Bs + (16 + lh) * 68 + lc) = b1;
        __syncthreads();
#pragma unroll
        for (int kk = 0; kk < 32; ++kk) {
            const float4 a = *(const float4*)(As + kk * 68 + ty * 4);
            const float4 b = *(const float4*)(Bs + kk * 68 + tx * 4);
            const float ar[4] = {a.x, a.y, a.z, a.w};
            const float br[4] = {b.x, b.y, b.z, b.w};
#pragma unroll
            for (int i = 0; i < 4; ++i)
#pragma unroll
                for (int j = 0; j < 4; ++j)
                    acc[i][j] = fmaf(ar[i], br[j], acc[i][j]);
        }
    }
#pragma unroll
    for (int i = 0; i < 4; ++i) {
        float4 o;
        o.x = acc[i][0]; o.y = acc[i][1]; o.z = acc[i][2]; o.w = acc[i][3];
        *(float4*)(Mg + (size_t)(ty * 4 + i) * N + col0 + tx * 4) = o;
    }
}

// ---------------------------------------------------------------------------
// Kernel E: dhw[g] = Z[:, g*64:(g+1)*64] @ M[g]   (NN GEMM, K=64)
// Z row-major ld 256; M[g] row-major [64, N]; out + g*B*N row-major.
// ---------------------------------------------------------------------------
__global__ __launch_bounds__(256) void k_dhw(
    const float* __restrict__ Z, const float* __restrict__ M,
    float* __restrict__ out, int N)
{
    const int g = blockIdx.z;
    const float* A  = Z + g * NZn;                 // ld 256
    const float* Bm = M + (size_t)g * NZn * N;     // [64, N]
    float* C = out + (size_t)g * Bn * N;

    __shared__ float As[16 * 68];
    __shared__ float Bs[16 * 68];
    float acc[4][4] = {};
    const int row0 = blockIdx.x * 64;
    const int col0 = blockIdx.y * 64;
    const int t = threadIdx.x;
    const int lr = t >> 2;          // A tile row
    const int lk = (t & 3) << 2;    // A tile k (float4)
    const int bk = t >> 4;          // B tile k row
    const int bc = (t & 15) * 4;    // B tile col (float4)
    const int ty = t >> 4, tx = t & 15;

    for (int k0 = 0; k0 < NZn; k0 += 16) {
        const float4 av = *(const float4*)(A  + (size_t)(row0 + lr) * HYPn + k0 + lk);
        const float4 bv = *(const float4*)(Bm + (size_t)(k0 + bk) * N + col0 + bc);
        __syncthreads();
        As[(lk + 0) * 68 + lr] = av.x;
        As[(lk + 1) * 68 + lr] = av.y;
        As[(lk + 2) * 68 + lr] = av.z;
        As[(lk + 3) * 68 + lr] = av.w;
        *(float4*)(Bs + bk * 68 + bc) = bv;
        __syncthreads();
#pragma unroll
        for (int kk = 0; kk < 16; ++kk) {
            const float4 a = *(const float4*)(As + kk * 68 + ty * 4);
            const float4 b = *(const float4*)(Bs + kk * 68 + tx * 4);
            const float ar[4] = {a.x, a.y, a.z, a.w};
            const float br[4] = {b.x, b.y, b.z, b.w};
#pragma unroll
            for (int i = 0; i < 4; ++i)
#pragma unroll
                for (int j = 0; j < 4; ++j)
                    acc[i][j] = fmaf(ar[i], br[j], acc[i][j]);
        }
    }
#pragma unroll
    for (int i = 0; i < 4; ++i) {
        float4 o;
        o.x = acc[i][0]; o.y = acc[i][1]; o.z = acc[i][2]; o.w = acc[i][3];
        *(float4*)(C + (size_t)(row0 + ty * 4 + i) * N + col0 + tx * 4) = o;
    }
}

// ---------------------------------------------------------------------------
extern "C" void kernel_launch(void* const* d_in, const int* in_sizes, int n_in,
                              void* d_out, int out_size, void* d_ws, size_t ws_size,
                              hipStream_t stream)
{
    // setup_inputs order; x (0), h (2), c (3) are unused by the reference.
    const float* e        = (const float*)d_in[1];
    const float* h_hat    = (const float*)d_in[4];
    const float* c_hat    = (const float*)d_in[5];
    const float* hyper_Wx = (const float*)d_in[6];
    const float* hyper_Wh = (const float*)d_in[7];
    const float* hyper_b  = (const float*)d_in[8];
    const float* ln_g     = (const float*)d_in[9];
    const float* ln_b     = (const float*)d_in[10];
    const float* lnc_g    = (const float*)d_in[11];
    const float* lnc_b    = (const float*)d_in[12];
    const float* zh_W     = (const float*)d_in[13];
    const float* zh_b     = (const float*)d_in[14];
    const float* zx_W     = (const float*)d_in[15];
    const float* zx_b     = (const float*)d_in[16];
    const float* zb_W     = (const float*)d_in[17];
    const float* dh_W     = (const float*)d_in[18];
    const float* dx_W     = (const float*)d_in[19];
    const float* w_h      = (const float*)d_in[20];
    const float* w_x      = (const float*)d_in[21];

    float* out1 = (float*)d_out;                        // dhw_h [4, B, HID]
    float* out2 = out1 + (size_t)4 * Bn * HIDn;         // dhw_x [4, B, IN]
    float* out3 = out2 + (size_t)4 * Bn * INn;          // z_b^T [4, B, NZ]

    float* ws   = (float*)d_ws;
    float* ifgo = ws;  ws += (size_t)Bn * 1024;         // 32 MiB
    float* hn   = ws;  ws += (size_t)Bn * HYPn;         //  8 MiB
    float* z_h  = ws;  ws += (size_t)Bn * HYPn;         //  8 MiB
    float* z_x  = ws;  ws += (size_t)Bn * HYPn;         //  8 MiB
    float* M_h  = ws;  ws += (size_t)4 * NZn * HIDn;    //  1 MiB
    float* M_x  = ws;  /* 4*64*512 */                   //  0.5 MiB

    // Independent precompute of the collapsed weight products.
    k_dm<<<dim3(16, 1, 4), 256, 0, stream>>>(dh_W, w_h, M_h, HIDn);
    k_dm<<<dim3(8, 1, 4), 256, 0, stream>>>(dx_W, w_x, M_x, INn);

    // Inner hyper-LSTM cell.
    k_ifgo<<<dim3(Bn / 64, (4 * HYPn) / 64), 256, 0, stream>>>(
        e, h_hat, hyper_Wx, hyper_Wh, hyper_b, ifgo);
    k_cell<<<dim3(Bn), 256, 0, stream>>>(ifgo, c_hat, ln_g, ln_b, lnc_g, lnc_b, hn);

    // z projections; z_b goes straight to out3 in [4, B, NZ] layout.
    k_z<<<dim3(Bn / 64, HYPn / 64), 256, 0, stream>>>(hn, zh_W, zh_b, z_h, 0);
    k_z<<<dim3(Bn / 64, HYPn / 64), 256, 0, stream>>>(hn, zx_W, zx_b, z_x, 0);
    k_z<<<dim3(Bn / 64, HYPn / 64), 256, 0, stream>>>(hn, zb_W, nullptr, out3, 1);

    // Final skinny-K GEMMs into the outputs.
    k_dhw<<<dim3(Bn / 64, HIDn / 64, 4), 256, 0, stream>>>(z_h, M_h, out1, HIDn);
    k_dhw<<<dim3(Bn / 64, INn / 64, 4), 256, 0, stream>>>(z_x, M_x, out2, INn);
}

// Round 8
// 512.394 us; speedup vs baseline: 1.4094x; 1.4094x over previous
//
#include <hip/hip_runtime.h>
#include <cstddef>

constexpr int Bn   = 8192;
constexpr int INn  = 512;
constexpr int EMBn = 512;
constexpr int HIDn = 1024;
constexpr int HYPn = 256;
constexpr int NZn  = 64;
constexpr float EPS = 1e-5f;

typedef unsigned short u16;
typedef unsigned int   u32;
typedef float f32x4 __attribute__((ext_vector_type(4)));
typedef short s16x8 __attribute__((ext_vector_type(8)));   // 8 bf16 (4 VGPRs), guide-verified frag type

// fp32 -> bf16 (round-to-nearest-even), pure bit ops (finite data only)
__device__ __forceinline__ u16 f2bf(float x) {
    u32 u = __float_as_uint(x);
    u = (u + 0x7FFFu + ((u >> 16) & 1u)) >> 16;
    return (u16)u;
}
__device__ __forceinline__ float bf2f(u16 h) {
    return __uint_as_float(((u32)h) << 16);
}

// ---------------------------------------------------------------------------
// k_prep: fp32 -> hi/lo bf16 planes in BLOCKED FRAGMENT ORDER.
// Chunk = 128 rows x 32 k = 512 units (unit = 16B = one lane's MFMA k-slice).
// Chunk order: row-block-major, then kblk. Within chunk:
//   unit = grp*64 + lane;  row = blk*128 + grp*16 + (lane&15);
//   k = kblk*32 + (lane>>4)*8.
// Main kernel then stages with linear global_load_lds and reads fragments
// with lane-linear ds_read_b128 (conflict-free), zero swizzle.
// ---------------------------------------------------------------------------
__global__ __launch_bounds__(256) void k_prep(
    const float* __restrict__ e,  const float* __restrict__ hh,
    const float* __restrict__ wx, const float* __restrict__ wh,
    u16* __restrict__ eHi, u16* __restrict__ eLo,
    u16* __restrict__ hhHi, u16* __restrict__ hhLo,
    u16* __restrict__ wxHi, u16* __restrict__ wxLo,
    u16* __restrict__ whHi, u16* __restrict__ whLo)
{
    long u = (long)blockIdx.x * 256 + threadIdx.x;
    const long U_E  = (long)Bn * EMBn / 8;     // 524288
    const long U_H  = (long)Bn * HYPn / 8;     // 262144
    const long U_WX = (long)HIDn * EMBn / 8;   // 65536
    const float* src; u16 *hi, *lo; int ld, kblks;
    if (u < U_E)                    { src = e;  hi = eHi;  lo = eLo;  ld = EMBn; kblks = EMBn / 32; }
    else if (u < U_E + U_H)         { u -= U_E; src = hh; hi = hhHi; lo = hhLo; ld = HYPn; kblks = HYPn / 32; }
    else if (u < U_E + U_H + U_WX)  { u -= U_E + U_H; src = wx; hi = wxHi; lo = wxLo; ld = EMBn; kblks = EMBn / 32; }
    else                            { u -= U_E + U_H + U_WX; src = wh; hi = whHi; lo = whLo; ld = HYPn; kblks = HYPn / 32; }

    const long lu = u;                       // segment-local unit index (dest)
    const long perBlk = (long)kblks * 512;   // units per 128-row block
    const int blk  = (int)(u / perBlk);
    const int rem  = (int)(u % perBlk);
    const int kblk = rem >> 9;
    const int r2   = rem & 511;
    const int grp  = r2 >> 6;
    const int lane = r2 & 63;
    const int row  = blk * 128 + grp * 16 + (lane & 15);
    const int k    = kblk * 32 + (lane >> 4) * 8;

    const float4 v0 = *(const float4*)(src + (size_t)row * ld + k);
    const float4 v1 = *(const float4*)(src + (size_t)row * ld + k + 4);
    const float f[8] = {v0.x, v0.y, v0.z, v0.w, v1.x, v1.y, v1.z, v1.w};
    union { u16 us[8]; uint4 v; } H, L;
#pragma unroll
    for (int j = 0; j < 8; ++j) {
        const u16 h = f2bf(f[j]);
        H.us[j] = h;
        L.us[j] = f2bf(f[j] - bf2f(h));
    }
    *(uint4*)(hi + lu * 8) = H.v;
    *(uint4*)(lo + lu * 8) = L.v;
}

// ---------------------------------------------------------------------------
// k_ifgo_mfma: ifgo[8192,1024] = e@Wx^T + h_hat@Wh^T + b via bf16 hi/lo
// 3-term MFMA (ah*bh + ah*bl + al*bh; dropped al*bl ~2^-18 relative).
// 128x128 tile, 4 waves (2x2, each 64x64 = 4x4 frags of 16x16x32), BK=32.
// LDS = 4 planes x 8KB = 32KB -> ~3 blocks/CU (m132: 64KB/2-blocks regime
// regressed 42% on the m97 ladder; avoid).
// ---------------------------------------------------------------------------
__global__ __launch_bounds__(256) void k_ifgo_mfma(
    const u16* __restrict__ eHi,  const u16* __restrict__ eLo,
    const u16* __restrict__ hhHi, const u16* __restrict__ hhLo,
    const u16* __restrict__ wxHi, const u16* __restrict__ wxLo,
    const u16* __restrict__ whHi, const u16* __restrict__ whLo,
    const float* __restrict__ bias, float* __restrict__ ifgo)
{
    __shared__ __align__(16) u16 lds[4 * 4096];   // 4 planes x 8KB
    const int t = threadIdx.x;
    const int w = t >> 6, l = t & 63;
    const int wr = w >> 1, wc = w & 1;
    const int bx = blockIdx.x, by = blockIdx.y;

    f32x4 acc[4][4] = {};

    for (int s = 0; s < 24; ++s) {
        const bool seg0 = s < 16;                  // e/Wx (K=512), then hh/Wh (K=256)
        const u16* aH = seg0 ? eHi  : hhHi;
        const u16* aL = seg0 ? eLo  : hhLo;
        const u16* bH = seg0 ? wxHi : whHi;
        const u16* bL = seg0 ? wxLo : whLo;
        const int kblks = seg0 ? 16 : 8;
        const int kb    = seg0 ? s : s - 16;
        const long ca = ((long)bx * kblks + kb) * 512;   // chunk base unit (A)
        const long cb = ((long)by * kblks + kb) * 512;   // chunk base unit (B)

        __syncthreads();   // previous compute done before LDS overwrite
#pragma unroll
        for (int i = 0; i < 2; ++i) {
            const int un = i * 256 + t;
            __builtin_amdgcn_global_load_lds(
                (const __attribute__((address_space(1))) u32*)(aH + (ca + un) * 8),
                (__attribute__((address_space(3))) u32*)(lds + 0 * 4096 + un * 8), 16, 0, 0);
            __builtin_amdgcn_global_load_lds(
                (const __attribute__((address_space(1))) u32*)(aL + (ca + un) * 8),
                (__attribute__((address_space(3))) u32*)(lds + 1 * 4096 + un * 8), 16, 0, 0);
            __builtin_amdgcn_global_load_lds(
                (const __attribute__((address_space(1))) u32*)(bH + (cb + un) * 8),
                (__attribute__((address_space(3))) u32*)(lds + 2 * 4096 + un * 8), 16, 0, 0);
            __builtin_amdgcn_global_load_lds(
                (const __attribute__((address_space(1))) u32*)(bL + (cb + un) * 8),
                (__attribute__((address_space(3))) u32*)(lds + 3 * 4096 + un * 8), 16, 0, 0);
        }
        __syncthreads();   // compiler drains vmcnt before s_barrier -> staged data visible

        s16x8 ah[4], al[4], bh[4], bl[4];
#pragma unroll
        for (int f = 0; f < 4; ++f) {
            const int ua = ((wr * 4 + f) * 64 + l) * 8;
            const int ub = ((wc * 4 + f) * 64 + l) * 8;
            ah[f] = *(const s16x8*)(lds + 0 * 4096 + ua);
            al[f] = *(const s16x8*)(lds + 1 * 4096 + ua);
            bh[f] = *(const s16x8*)(lds + 2 * 4096 + ub);
            bl[f] = *(const s16x8*)(lds + 3 * 4096 + ub);
        }
#pragma unroll
        for (int fm = 0; fm < 4; ++fm)
#pragma unroll
            for (int fn = 0; fn < 4; ++fn) {
                acc[fm][fn] = __builtin_amdgcn_mfma_f32_16x16x32_bf16(ah[fm], bh[fn], acc[fm][fn], 0, 0, 0);
                acc[fm][fn] = __builtin_amdgcn_mfma_f32_16x16x32_bf16(ah[fm], bl[fn], acc[fm][fn], 0, 0, 0);
                acc[fm][fn] = __builtin_amdgcn_mfma_f32_16x16x32_bf16(al[fm], bh[fn], acc[fm][fn], 0, 0, 0);
            }
    }

    // Epilogue: C/D layout col = lane&15, row = (lane>>4)*4 + reg  [m89/m91]
    const int row0 = bx * 128 + wr * 64;
    const int col0 = by * 128 + wc * 64;
    float bv[4];
#pragma unroll
    for (int fn = 0; fn < 4; ++fn) bv[fn] = bias[col0 + fn * 16 + (l & 15)];
#pragma unroll
    for (int fm = 0; fm < 4; ++fm) {
        const int r0 = row0 + fm * 16 + (l >> 4) * 4;
#pragma unroll
        for (int fn = 0; fn < 4; ++fn) {
            const int c = col0 + fn * 16 + (l & 15);
#pragma unroll
            for (int r = 0; r < 4; ++r)
                ifgo[(size_t)(r0 + r) * (4 * HYPn) + c] = acc[fm][fn][r] + bv[fn];
        }
    }
}

// ---------------------------------------------------------------------------
// Shared fp32 NT-GEMM tile accumulator: C64x64 += A@B^T (verified R0)
// ---------------------------------------------------------------------------
__device__ __forceinline__ void nt_accum(
    const float* __restrict__ A, const float* __restrict__ Bm,
    int K, int lda, int ldb, int row0, int col0, int t,
    float acc[4][4], float* As, float* Bs)
{
    const int lr = t >> 2;
    const int lk = (t & 3) << 2;
    const int ty = t >> 4;
    const int tx = t & 15;
    for (int k0 = 0; k0 < K; k0 += 16) {
        const float4 av = *(const float4*)(A  + (size_t)(row0 + lr) * lda + k0 + lk);
        const float4 bv = *(const float4*)(Bm + (size_t)(col0 + lr) * ldb + k0 + lk);
        __syncthreads();
        As[(lk + 0) * 68 + lr] = av.x; As[(lk + 1) * 68 + lr] = av.y;
        As[(lk + 2) * 68 + lr] = av.z; As[(lk + 3) * 68 + lr] = av.w;
        Bs[(lk + 0) * 68 + lr] = bv.x; Bs[(lk + 1) * 68 + lr] = bv.y;
        Bs[(lk + 2) * 68 + lr] = bv.z; Bs[(lk + 3) * 68 + lr] = bv.w;
        __syncthreads();
#pragma unroll
        for (int kk = 0; kk < 16; ++kk) {
            const float4 a = *(const float4*)(As + kk * 68 + ty * 4);
            const float4 b = *(const float4*)(Bs + kk * 68 + tx * 4);
            const float ar[4] = {a.x, a.y, a.z, a.w};
            const float br[4] = {b.x, b.y, b.z, b.w};
#pragma unroll
            for (int i = 0; i < 4; ++i)
#pragma unroll
                for (int j = 0; j < 4; ++j)
                    acc[i][j] = fmaf(ar[i], br[j], acc[i][j]);
        }
    }
}

// ---------------------------------------------------------------------------
// k_cell: per-row hyper LSTM cell (unchanged, verified R0)
// ---------------------------------------------------------------------------
__global__ __launch_bounds__(256) void k_cell(
    const float* __restrict__ ifgo, const float* __restrict__ c_hat,
    const float* __restrict__ ln_g, const float* __restrict__ ln_b,
    const float* __restrict__ lnc_g, const float* __restrict__ lnc_b,
    float* __restrict__ h_hat_n)
{
    const int row = blockIdx.x;
    const int t = threadIdx.x;
    const int lane = t & 63;
    const int wid = t >> 6;

    __shared__ float act[4][256];
    __shared__ float red[8];

    const float4 v = *(const float4*)(ifgo + (size_t)row * 1024 + t * 4);
    float s  = v.x + v.y + v.z + v.w;
    float ss = v.x * v.x + v.y * v.y + v.z * v.z + v.w * v.w;
#pragma unroll
    for (int off = 32; off > 0; off >>= 1) {
        s  += __shfl_xor(s, off);
        ss += __shfl_xor(ss, off);
    }
    const float m    = s * (1.f / 256.f);
    const float var  = fmaxf(ss * (1.f / 256.f) - m * m, 0.f);
    const float rstd = rsqrtf(var + EPS);

    const int jb = lane * 4;
    const float4 g4 = *(const float4*)(ln_g + wid * 256 + jb);
    const float4 b4 = *(const float4*)(ln_b + wid * 256 + jb);
    float y[4];
    y[0] = (v.x - m) * rstd * g4.x + b4.x;
    y[1] = (v.y - m) * rstd * g4.y + b4.y;
    y[2] = (v.z - m) * rstd * g4.z + b4.z;
    y[3] = (v.w - m) * rstd * g4.w + b4.w;
#pragma unroll
    for (int k = 0; k < 4; ++k) {
        float a;
        if (wid == 2) a = tanhf(y[k]);
        else          a = 1.f / (1.f + expf(-y[k]));
        act[wid][jb + k] = a;
    }
    __syncthreads();

    const float si = act[0][t];
    const float sf = act[1][t];
    const float tg = act[2][t];
    const float so = act[3][t];
    const float cn = sf * c_hat[(size_t)row * 256 + t] + si * tg;

    float s2 = cn, ss2 = cn * cn;
#pragma unroll
    for (int off = 32; off > 0; off >>= 1) {
        s2  += __shfl_xor(s2, off);
        ss2 += __shfl_xor(ss2, off);
    }
    if (lane == 0) { red[wid] = s2; red[4 + wid] = ss2; }
    __syncthreads();
    const float tot  = red[0] + red[1] + red[2] + red[3];
    const float tots = red[4] + red[5] + red[6] + red[7];
    const float m2   = tot * (1.f / 256.f);
    const float var2 = fmaxf(tots * (1.f / 256.f) - m2 * m2, 0.f);
    const float r2   = rsqrtf(var2 + EPS);
    const float hn   = so * tanhf((cn - m2) * r2 * lnc_g[t] + lnc_b[t]);
    h_hat_n[(size_t)row * 256 + t] = hn;
}

// ---------------------------------------------------------------------------
// k_z_all: all three z projections in ONE launch. blockIdx.y in [0,12):
// seg = y>>2 (0:z_h+bias, 1:z_x+bias, 2:z_b -> out3 [4,B,64]), col0=(y&3)*64.
// ---------------------------------------------------------------------------
__global__ __launch_bounds__(256) void k_z_all(
    const float* __restrict__ hn,
    const float* __restrict__ zh_W, const float* __restrict__ zh_b,
    const float* __restrict__ zx_W, const float* __restrict__ zx_b,
    const float* __restrict__ zb_W,
    float* __restrict__ z_h, float* __restrict__ z_x, float* __restrict__ out3)
{
    __shared__ float As[16 * 68];
    __shared__ float Bs[16 * 68];
    float acc[4][4] = {};
    const int row0 = blockIdx.x * 64;
    const int seg  = blockIdx.y >> 2;
    const int col0 = (blockIdx.y & 3) * 64;
    const int t = threadIdx.x;

    const float* W = seg == 0 ? zh_W : (seg == 1 ? zx_W : zb_W);
    nt_accum(hn, W, HYPn, HYPn, HYPn, row0, col0, t, acc, As, Bs);

    const int ty = t >> 4, tx = t & 15;
    if (seg < 2) {
        const float* bias = seg == 0 ? zh_b : zx_b;
        float* out = seg == 0 ? z_h : z_x;
        const float4 bv = *(const float4*)(bias + col0 + tx * 4);
#pragma unroll
        for (int i = 0; i < 4; ++i) {
            float4 o;
            o.x = acc[i][0] + bv.x; o.y = acc[i][1] + bv.y;
            o.z = acc[i][2] + bv.z; o.w = acc[i][3] + bv.w;
            *(float4*)(out + (size_t)(row0 + ty * 4 + i) * 256 + col0 + tx * 4) = o;
        }
    } else {
        const int g = blockIdx.y & 3;
#pragma unroll
        for (int i = 0; i < 4; ++i) {
            float4 o;
            o.x = acc[i][0]; o.y = acc[i][1]; o.z = acc[i][2]; o.w = acc[i][3];
            *(float4*)(out3 + ((size_t)g * Bn + row0 + ty * 4 + i) * 64 + tx * 4) = o;
        }
    }
}

// ---------------------------------------------------------------------------
// k_dm_part: split-K (4 ways over h=1024) of M[g] = dW[g]^T @ w[g].
// blockIdx = (colblk, split, tensor*4+gate). Both tensors in one launch.
// ---------------------------------------------------------------------------
__global__ __launch_bounds__(256) void k_dm_part(
    const float* __restrict__ dh_W, const float* __restrict__ w_h,
    const float* __restrict__ dx_W, const float* __restrict__ w_x,
    float* __restrict__ pH, float* __restrict__ pX)
{
    const int tens = blockIdx.z >> 2;
    const int g    = blockIdx.z & 3;
    const int N    = tens ? INn : HIDn;
    if ((int)blockIdx.x * 64 >= N) return;
    const float* A  = (tens ? dx_W : dh_W) + (size_t)g * HIDn * NZn;   // [1024,64]
    const float* Bw = (tens ? w_x  : w_h ) + (size_t)g * HIDn * N;     // [1024,N]
    float* P = (tens ? pX : pH) + ((size_t)(g * 4 + blockIdx.y) * 64) * N;
    const int col0 = blockIdx.x * 64;
    const int hb   = blockIdx.y * 256;
    const int t = threadIdx.x;

    __shared__ float As[32 * 68];
    __shared__ float Bs[32 * 68];
    float acc[4][4] = {};
    const int lh = t >> 4;
    const int lc = (t & 15) * 4;
    const int ty = t >> 4, tx = t & 15;

    for (int h0 = hb; h0 < hb + 256; h0 += 32) {
        const float4 a0 = *(const float4*)(A  + (size_t)(h0 + lh)      * NZn + lc);
        const float4 a1 = *(const float4*)(A  + (size_t)(h0 + 16 + lh) * NZn + lc);
        const float4 b0 = *(const float4*)(Bw + (size_t)(h0 + lh)      * N + col0 + lc);
        const float4 b1 = *(const float4*)(Bw + (size_t)(h0 + 16 + lh) * N + col0 + lc);
        __syncthreads();
        *(float4*)(As + lh * 68 + lc)        = a0;
        *(float4*)(As + (16 + lh) * 68 + lc) = a1;
        *(float4*)(Bs + lh * 68 + lc)        = b0;
        *(float4*)(Bs + (16 + lh) * 68 + lc) = b1;
        __syncthreads();
#pragma unroll
        for (int kk = 0; kk < 32; ++kk) {
            const float4 a = *(const float4*)(As + kk * 68 + ty * 4);
            const float4 b = *(const float4*)(Bs + kk * 68 + tx * 4);
            const float ar[4] = {a.x, a.y, a.z, a.w};
            const float br[4] = {b.x, b.y, b.z, b.w};
#pragma unroll
            for (int i = 0; i < 4; ++i)
#pragma unroll
                for (int j = 0; j < 4; ++j)
                    acc[i][j] = fmaf(ar[i], br[j], acc[i][j]);
        }
    }
#pragma unroll
    for (int i = 0; i < 4; ++i) {
        float4 o;
        o.x = acc[i][0]; o.y = acc[i][1]; o.z = acc[i][2]; o.w = acc[i][3];
        *(float4*)(P + (size_t)(ty * 4 + i) * N + col0 + tx * 4) = o;
    }
}

// k_red: M = sum of 4 split partials (both tensors, one launch, float4/thread)
__global__ __launch_bounds__(256) void k_red(
    const float* __restrict__ pH, const float* __restrict__ pX,
    float* __restrict__ M_h, float* __restrict__ M_x)
{
    const int NH4 = 4 * 64 * 1024 / 4;   // 65536
    const int id = blockIdx.x * 256 + threadIdx.x;
    if (id < NH4) {
        const int per = 64 * 1024 / 4;   // 16384 float4 per (g,split)
        const int g = id / per, r = id % per;
        const float4* b = (const float4*)pH + (size_t)g * 4 * per + r;
        const float4 a0 = b[0], a1 = b[per], a2 = b[2 * per], a3 = b[3 * per];
        float4 o;
        o.x = a0.x + a1.x + a2.x + a3.x; o.y = a0.y + a1.y + a2.y + a3.y;
        o.z = a0.z + a1.z + a2.z + a3.z; o.w = a0.w + a1.w + a2.w + a3.w;
        ((float4*)M_h)[id] = o;
    } else {
        const int id2 = id - NH4;
        const int per = 64 * 512 / 4;    // 8192
        const int g = id2 / per, r = id2 % per;
        const float4* b = (const float4*)pX + (size_t)g * 4 * per + r;
        const float4 a0 = b[0], a1 = b[per], a2 = b[2 * per], a3 = b[3 * per];
        float4 o;
        o.x = a0.x + a1.x + a2.x + a3.x; o.y = a0.y + a1.y + a2.y + a3.y;
        o.z = a0.z + a1.z + a2.z + a3.z; o.w = a0.w + a1.w + a2.w + a3.w;
        ((float4*)M_x)[id2] = o;
    }
}

// ---------------------------------------------------------------------------
// k_dhw: dhw[g] = Z[:, g*64:(g+1)*64] @ M[g]  (NN, K=64) — unchanged from R0
// ---------------------------------------------------------------------------
__global__ __launch_bounds__(256) void k_dhw(
    const float* __restrict__ Z, const float* __restrict__ M,
    float* __restrict__ out, int N)
{
    const int g = blockIdx.z;
    const float* A  = Z + g * NZn;
    const float* Bm = M + (size_t)g * NZn * N;
    float* C = out + (size_t)g * Bn * N;

    __shared__ float As[16 * 68];
    __shared__ float Bs[16 * 68];
    float acc[4][4] = {};
    const int row0 = blockIdx.x * 64;
    const int col0 = blockIdx.y * 64;
    const int t = threadIdx.x;
    const int lr = t >> 2;
    const int lk = (t & 3) << 2;
    const int bk = t >> 4;
    const int bc = (t & 15) * 4;
    const int ty = t >> 4, tx = t & 15;

    for (int k0 = 0; k0 < NZn; k0 += 16) {
        const float4 av = *(const float4*)(A  + (size_t)(row0 + lr) * HYPn + k0 + lk);
        const float4 bv = *(const float4*)(Bm + (size_t)(k0 + bk) * N + col0 + bc);
        __syncthreads();
        As[(lk + 0) * 68 + lr] = av.x; As[(lk + 1) * 68 + lr] = av.y;
        As[(lk + 2) * 68 + lr] = av.z; As[(lk + 3) * 68 + lr] = av.w;
        *(float4*)(Bs + bk * 68 + bc) = bv;
        __syncthreads();
#pragma unroll
        for (int kk = 0; kk < 16; ++kk) {
            const float4 a = *(const float4*)(As + kk * 68 + ty * 4);
            const float4 b = *(const float4*)(Bs + kk * 68 + tx * 4);
            const float ar[4] = {a.x, a.y, a.z, a.w};
            const float br[4] = {b.x, b.y, b.z, b.w};
#pragma unroll
            for (int i = 0; i < 4; ++i)
#pragma unroll
                for (int j = 0; j < 4; ++j)
                    acc[i][j] = fmaf(ar[i], br[j], acc[i][j]);
        }
    }
#pragma unroll
    for (int i = 0; i < 4; ++i) {
        float4 o;
        o.x = acc[i][0]; o.y = acc[i][1]; o.z = acc[i][2]; o.w = acc[i][3];
        *(float4*)(C + (size_t)(row0 + ty * 4 + i) * N + col0 + tx * 4) = o;
    }
}

// ---------------------------------------------------------------------------
extern "C" void kernel_launch(void* const* d_in, const int* in_sizes, int n_in,
                              void* d_out, int out_size, void* d_ws, size_t ws_size,
                              hipStream_t stream)
{
    const float* e        = (const float*)d_in[1];
    const float* h_hat    = (const float*)d_in[4];
    const float* c_hat    = (const float*)d_in[5];
    const float* hyper_Wx = (const float*)d_in[6];
    const float* hyper_Wh = (const float*)d_in[7];
    const float* hyper_b  = (const float*)d_in[8];
    const float* ln_g     = (const float*)d_in[9];
    const float* ln_b     = (const float*)d_in[10];
    const float* lnc_g    = (const float*)d_in[11];
    const float* lnc_b    = (const float*)d_in[12];
    const float* zh_W     = (const float*)d_in[13];
    const float* zh_b     = (const float*)d_in[14];
    const float* zx_W     = (const float*)d_in[15];
    const float* zx_b     = (const float*)d_in[16];
    const float* zb_W     = (const float*)d_in[17];
    const float* dh_W     = (const float*)d_in[18];
    const float* dx_W     = (const float*)d_in[19];
    const float* w_h      = (const float*)d_in[20];
    const float* w_x      = (const float*)d_in[21];

    float* out1 = (float*)d_out;                        // dhw_h [4, B, HID]
    float* out2 = out1 + (size_t)4 * Bn * HIDn;         // dhw_x [4, B, IN]
    float* out3 = out2 + (size_t)4 * Bn * INn;          // z_b^T [4, B, NZ]

    float* ws   = (float*)d_ws;
    float* ifgo = ws;  ws += (size_t)Bn * 1024;         // 32 MiB
    float* hn   = ws;  ws += (size_t)Bn * HYPn;         //  8 MiB
    float* z_h  = ws;  ws += (size_t)Bn * HYPn;         //  8 MiB
    float* z_x  = ws;  ws += (size_t)Bn * HYPn;         //  8 MiB
    float* M_h  = ws;  ws += (size_t)4 * NZn * HIDn;    //  1 MiB
    float* M_x  = ws;  ws += (size_t)4 * NZn * INn;     //  0.5 MiB
    float* pH   = ws;  ws += (size_t)16 * NZn * HIDn;   //  4 MiB
    float* pX   = ws;  ws += (size_t)16 * NZn * INn;    //  2 MiB
    u16* bp   = (u16*)ws;
    u16* eHi  = bp;  bp += (size_t)Bn * EMBn;
    u16* eLo  = bp;  bp += (size_t)Bn * EMBn;
    u16* hhHi = bp;  bp += (size_t)Bn * HYPn;
    u16* hhLo = bp;  bp += (size_t)Bn * HYPn;
    u16* wxHi = bp;  bp += (size_t)HIDn * EMBn;
    u16* wxLo = bp;  bp += (size_t)HIDn * EMBn;
    u16* whHi = bp;  bp += (size_t)HIDn * HYPn;
    u16* whLo = bp;  bp += (size_t)HIDn * HYPn;

    // 1. bf16 hi/lo plane prep (blocked fragment order)
    k_prep<<<dim3(3456), 256, 0, stream>>>(e, h_hat, hyper_Wx, hyper_Wh,
        eHi, eLo, hhHi, hhLo, wxHi, wxLo, whHi, whLo);
    // 2. collapsed weight products (split-K x4, both tensors) + reduce
    k_dm_part<<<dim3(16, 4, 8), 256, 0, stream>>>(dh_W, w_h, dx_W, w_x, pH, pX);
    k_red<<<dim3(384), 256, 0, stream>>>(pH, pX, M_h, M_x);
    // 3. inner cell: MFMA ifgo then per-row LN/gates
    k_ifgo_mfma<<<dim3(64, 8), 256, 0, stream>>>(
        eHi, eLo, hhHi, hhLo, wxHi, wxLo, whHi, whLo, hyper_b, ifgo);
    k_cell<<<dim3(Bn), 256, 0, stream>>>(ifgo, c_hat, ln_g, ln_b, lnc_g, lnc_b, hn);
    // 4. z projections (one launch)
    k_z_all<<<dim3(Bn / 64, 12), 256, 0, stream>>>(
        hn, zh_W, zh_b, zx_W, zx_b, zb_W, z_h, z_x, out3);
    // 5. output GEMMs
    k_dhw<<<dim3(Bn / 64, HIDn / 64, 4), 256, 0, stream>>>(z_h, M_h, out1, HIDn);
    k_dhw<<<dim3(Bn / 64, INn / 64, 4), 256, 0, stream>>>(z_x, M_x, out2, INn);
}

// Round 11
// 495.219 us; speedup vs baseline: 1.4583x; 1.0347x over previous
//
#include <hip/hip_runtime.h>
#include <cstddef>

constexpr int Bn   = 8192;
constexpr int INn  = 512;
constexpr int EMBn = 512;
constexpr int HIDn = 1024;
constexpr int HYPn = 256;
constexpr int NZn  = 64;
constexpr float EPS = 1e-5f;

typedef unsigned short u16;
typedef unsigned int   u32;
typedef float f32x4 __attribute__((ext_vector_type(4)));
typedef short s16x8 __attribute__((ext_vector_type(8)));   // 8 bf16 frag (HW-verified R8)

__device__ __forceinline__ u16 f2bf(float x) {
    u32 u = __float_as_uint(x);
    u = (u + 0x7FFFu + ((u >> 16) & 1u)) >> 16;
    return (u16)u;
}
__device__ __forceinline__ float bf2f(u16 h) {
    return __uint_as_float(((u32)h) << 16);
}

// ---------------------------------------------------------------------------
// k_prep: fp32 -> hi/lo bf16 planes in blocked fragment order (HW-verified).
// Chunk = 128 rows x 32 k = 512 units; unit = grp*64+lane;
// row = blk*128+grp*16+(lane&15); k = kblk*32+(lane>>4)*8.
// Segments: e, h_hat, Wx, Wh, zb_W (zb_W: B operand of k_out).
// ---------------------------------------------------------------------------
__global__ __launch_bounds__(256) void k_prep(
    const float* __restrict__ e,  const float* __restrict__ hh,
    const float* __restrict__ wx, const float* __restrict__ wh,
    const float* __restrict__ zb,
    u16* __restrict__ eHi, u16* __restrict__ eLo,
    u16* __restrict__ hhHi, u16* __restrict__ hhLo,
    u16* __restrict__ wxHi, u16* __restrict__ wxLo,
    u16* __restrict__ whHi, u16* __restrict__ whLo,
    u16* __restrict__ zbHi, u16* __restrict__ zbLo)
{
    long u = (long)blockIdx.x * 256 + threadIdx.x;
    const long U_E  = (long)Bn * EMBn / 8;     // 524288
    const long U_H  = (long)Bn * HYPn / 8;     // 262144
    const long U_WX = (long)HIDn * EMBn / 8;   // 65536
    const long U_WH = (long)HIDn * HYPn / 8;   // 32768
    const float* src; u16 *hi, *lo; int ld, kblks;
    if (u < U_E)                          { src = e;  hi = eHi;  lo = eLo;  ld = EMBn; kblks = EMBn / 32; }
    else if (u < U_E + U_H)               { u -= U_E; src = hh; hi = hhHi; lo = hhLo; ld = HYPn; kblks = HYPn / 32; }
    else if (u < U_E + U_H + U_WX)        { u -= U_E + U_H; src = wx; hi = wxHi; lo = wxLo; ld = EMBn; kblks = EMBn / 32; }
    else if (u < U_E + U_H + U_WX + U_WH) { u -= U_E + U_H + U_WX; src = wh; hi = whHi; lo = whLo; ld = HYPn; kblks = HYPn / 32; }
    else                                  { u -= U_E + U_H + U_WX + U_WH; src = zb; hi = zbHi; lo = zbLo; ld = HYPn; kblks = HYPn / 32; }

    const long lu = u;
    const long perBlk = (long)kblks * 512;
    const int blk  = (int)(u / perBlk);
    const int rem  = (int)(u % perBlk);
    const int kblk = rem >> 9;
    const int r2   = rem & 511;
    const int grp  = r2 >> 6;
    const int lane = r2 & 63;
    const int row  = blk * 128 + grp * 16 + (lane & 15);
    const int k    = kblk * 32 + (lane >> 4) * 8;

    const float4 v0 = *(const float4*)(src + (size_t)row * ld + k);
    const float4 v1 = *(const float4*)(src + (size_t)row * ld + k + 4);
    const float f[8] = {v0.x, v0.y, v0.z, v0.w, v1.x, v1.y, v1.z, v1.w};
    union { u16 us[8]; uint4 v; } H, L;
#pragma unroll
    for (int j = 0; j < 8; ++j) {
        const u16 h = f2bf(f[j]);
        H.us[j] = h;
        L.us[j] = f2bf(f[j] - bf2f(h));
    }
    *(uint4*)(hi + lu * 8) = H.v;
    *(uint4*)(lo + lu * 8) = L.v;
}

// k_prep1: same conversion for hn [8192, 256] only (runs after k_cell)
__global__ __launch_bounds__(256) void k_prep1(
    const float* __restrict__ src, u16* __restrict__ hi, u16* __restrict__ lo)
{
    const long u = (long)blockIdx.x * 256 + threadIdx.x;   // < 262144
    const int blk  = (int)(u >> 12);           // perBlk = 8*512 = 4096
    const int rem  = (int)(u & 4095);
    const int kblk = rem >> 9;
    const int r2   = rem & 511;
    const int lane = r2 & 63;
    const int row  = blk * 128 + (r2 >> 6) * 16 + (lane & 15);
    const int k    = kblk * 32 + (lane >> 4) * 8;

    const float4 v0 = *(const float4*)(src + (size_t)row * HYPn + k);
    const float4 v1 = *(const float4*)(src + (size_t)row * HYPn + k + 4);
    const float f[8] = {v0.x, v0.y, v0.z, v0.w, v1.x, v1.y, v1.z, v1.w};
    union { u16 us[8]; uint4 v; } H, L;
#pragma unroll
    for (int j = 0; j < 8; ++j) {
        const u16 h = f2bf(f[j]);
        H.us[j] = h;
        L.us[j] = f2bf(f[j] - bf2f(h));
    }
    *(uint4*)(hi + u * 8) = H.v;
    *(uint4*)(lo + u * 8) = L.v;
}

// ---------------------------------------------------------------------------
// k_ifgo_mfma: unchanged (HW-verified R8, <127 us, absmax OK)
// ---------------------------------------------------------------------------
__global__ __launch_bounds__(256) void k_ifgo_mfma(
    const u16* __restrict__ eHi,  const u16* __restrict__ eLo,
    const u16* __restrict__ hhHi, const u16* __restrict__ hhLo,
    const u16* __restrict__ wxHi, const u16* __restrict__ wxLo,
    const u16* __restrict__ whHi, const u16* __restrict__ whLo,
    const float* __restrict__ bias, float* __restrict__ ifgo)
{
    __shared__ __align__(16) u16 lds[4 * 4096];
    const int t = threadIdx.x;
    const int w = t >> 6, l = t & 63;
    const int wr = w >> 1, wc = w & 1;
    const int bx = blockIdx.x, by = blockIdx.y;

    f32x4 acc[4][4] = {};

    for (int s = 0; s < 24; ++s) {
        const bool seg0 = s < 16;
        const u16* aH = seg0 ? eHi  : hhHi;
        const u16* aL = seg0 ? eLo  : hhLo;
        const u16* bH = seg0 ? wxHi : whHi;
        const u16* bL = seg0 ? wxLo : whLo;
        const int kblks = seg0 ? 16 : 8;
        const int kb    = seg0 ? s : s - 16;
        const long ca = ((long)bx * kblks + kb) * 512;
        const long cb = ((long)by * kblks + kb) * 512;

        __syncthreads();
#pragma unroll
        for (int i = 0; i < 2; ++i) {
            const int un = i * 256 + t;
            __builtin_amdgcn_global_load_lds(
                (const __attribute__((address_space(1))) u32*)(aH + (ca + un) * 8),
                (__attribute__((address_space(3))) u32*)(lds + 0 * 4096 + un * 8), 16, 0, 0);
            __builtin_amdgcn_global_load_lds(
                (const __attribute__((address_space(1))) u32*)(aL + (ca + un) * 8),
                (__attribute__((address_space(3))) u32*)(lds + 1 * 4096 + un * 8), 16, 0, 0);
            __builtin_amdgcn_global_load_lds(
                (const __attribute__((address_space(1))) u32*)(bH + (cb + un) * 8),
                (__attribute__((address_space(3))) u32*)(lds + 2 * 4096 + un * 8), 16, 0, 0);
            __builtin_amdgcn_global_load_lds(
                (const __attribute__((address_space(1))) u32*)(bL + (cb + un) * 8),
                (__attribute__((address_space(3))) u32*)(lds + 3 * 4096 + un * 8), 16, 0, 0);
        }
        __syncthreads();

        s16x8 ah[4], al[4], bh[4], bl[4];
#pragma unroll
        for (int f = 0; f < 4; ++f) {
            const int ua = ((wr * 4 + f) * 64 + l) * 8;
            const int ub = ((wc * 4 + f) * 64 + l) * 8;
            ah[f] = *(const s16x8*)(lds + 0 * 4096 + ua);
            al[f] = *(const s16x8*)(lds + 1 * 4096 + ua);
            bh[f] = *(const s16x8*)(lds + 2 * 4096 + ub);
            bl[f] = *(const s16x8*)(lds + 3 * 4096 + ub);
        }
#pragma unroll
        for (int fm = 0; fm < 4; ++fm)
#pragma unroll
            for (int fn = 0; fn < 4; ++fn) {
                acc[fm][fn] = __builtin_amdgcn_mfma_f32_16x16x32_bf16(ah[fm], bh[fn], acc[fm][fn], 0, 0, 0);
                acc[fm][fn] = __builtin_amdgcn_mfma_f32_16x16x32_bf16(ah[fm], bl[fn], acc[fm][fn], 0, 0, 0);
                acc[fm][fn] = __builtin_amdgcn_mfma_f32_16x16x32_bf16(al[fm], bh[fn], acc[fm][fn], 0, 0, 0);
            }
    }

    const int row0 = bx * 128 + wr * 64;
    const int col0 = by * 128 + wc * 64;
    float bv[4];
#pragma unroll
    for (int fn = 0; fn < 4; ++fn) bv[fn] = bias[col0 + fn * 16 + (l & 15)];
#pragma unroll
    for (int fm = 0; fm < 4; ++fm) {
        const int r0 = row0 + fm * 16 + (l >> 4) * 4;
#pragma unroll
        for (int fn = 0; fn < 4; ++fn) {
            const int c = col0 + fn * 16 + (l & 15);
#pragma unroll
            for (int r = 0; r < 4; ++r)
                ifgo[(size_t)(r0 + r) * (4 * HYPn) + c] = acc[fm][fn][r] + bv[fn];
        }
    }
}

// ---------------------------------------------------------------------------
// k_cell: unchanged (verified R0/R8)
// ---------------------------------------------------------------------------
__global__ __launch_bounds__(256) void k_cell(
    const float* __restrict__ ifgo, const float* __restrict__ c_hat,
    const float* __restrict__ ln_g, const float* __restrict__ ln_b,
    const float* __restrict__ lnc_g, const float* __restrict__ lnc_b,
    float* __restrict__ h_hat_n)
{
    const int row = blockIdx.x;
    const int t = threadIdx.x;
    const int lane = t & 63;
    const int wid = t >> 6;

    __shared__ float act[4][256];
    __shared__ float red[8];

    const float4 v = *(const float4*)(ifgo + (size_t)row * 1024 + t * 4);
    float s  = v.x + v.y + v.z + v.w;
    float ss = v.x * v.x + v.y * v.y + v.z * v.z + v.w * v.w;
#pragma unroll
    for (int off = 32; off > 0; off >>= 1) {
        s  += __shfl_xor(s, off);
        ss += __shfl_xor(ss, off);
    }
    const float m    = s * (1.f / 256.f);
    const float var  = fmaxf(ss * (1.f / 256.f) - m * m, 0.f);
    const float rstd = rsqrtf(var + EPS);

    const int jb = lane * 4;
    const float4 g4 = *(const float4*)(ln_g + wid * 256 + jb);
    const float4 b4 = *(const float4*)(ln_b + wid * 256 + jb);
    float y[4];
    y[0] = (v.x - m) * rstd * g4.x + b4.x;
    y[1] = (v.y - m) * rstd * g4.y + b4.y;
    y[2] = (v.z - m) * rstd * g4.z + b4.z;
    y[3] = (v.w - m) * rstd * g4.w + b4.w;
#pragma unroll
    for (int k = 0; k < 4; ++k) {
        float a;
        if (wid == 2) a = tanhf(y[k]);
        else          a = 1.f / (1.f + expf(-y[k]));
        act[wid][jb + k] = a;
    }
    __syncthreads();

    const float si = act[0][t];
    const float sf = act[1][t];
    const float tg = act[2][t];
    const float so = act[3][t];
    const float cn = sf * c_hat[(size_t)row * 256 + t] + si * tg;

    float s2 = cn, ss2 = cn * cn;
#pragma unroll
    for (int off = 32; off > 0; off >>= 1) {
        s2  += __shfl_xor(s2, off);
        ss2 += __shfl_xor(ss2, off);
    }
    if (lane == 0) { red[wid] = s2; red[4 + wid] = ss2; }
    __syncthreads();
    const float tot  = red[0] + red[1] + red[2] + red[3];
    const float tots = red[4] + red[5] + red[6] + red[7];
    const float m2   = tot * (1.f / 256.f);
    const float var2 = fmaxf(tots * (1.f / 256.f) - m2 * m2, 0.f);
    const float r2   = rsqrtf(var2 + EPS);
    const float hn   = so * tanhf((cn - m2) * r2 * lnc_g[t] + lnc_b[t]);
    h_hat_n[(size_t)row * 256 + t] = hn;
}

// ---------------------------------------------------------------------------
// k_dm_part / k_red: unchanged (split-K M[g] = dW[g]^T @ w[g])
// ---------------------------------------------------------------------------
__global__ __launch_bounds__(256) void k_dm_part(
    const float* __restrict__ dh_W, const float* __restrict__ w_h,
    const float* __restrict__ dx_W, const float* __restrict__ w_x,
    float* __restrict__ pH, float* __restrict__ pX)
{
    const int tens = blockIdx.z >> 2;
    const int g    = blockIdx.z & 3;
    const int N    = tens ? INn : HIDn;
    if ((int)blockIdx.x * 64 >= N) return;
    const float* A  = (tens ? dx_W : dh_W) + (size_t)g * HIDn * NZn;
    const float* Bw = (tens ? w_x  : w_h ) + (size_t)g * HIDn * N;
    float* P = (tens ? pX : pH) + ((size_t)(g * 4 + blockIdx.y) * 64) * N;
    const int col0 = blockIdx.x * 64;
    const int hb   = blockIdx.y * 256;
    const int t = threadIdx.x;

    __shared__ float As[32 * 68];
    __shared__ float Bs[32 * 68];
    float acc[4][4] = {};
    const int lh = t >> 4;
    const int lc = (t & 15) * 4;
    const int ty = t >> 4, tx = t & 15;

    for (int h0 = hb; h0 < hb + 256; h0 += 32) {
        const float4 a0 = *(const float4*)(A  + (size_t)(h0 + lh)      * NZn + lc);
        const float4 a1 = *(const float4*)(A  + (size_t)(h0 + 16 + lh) * NZn + lc);
        const float4 b0 = *(const float4*)(Bw + (size_t)(h0 + lh)      * N + col0 + lc);
        const float4 b1 = *(const float4*)(Bw + (size_t)(h0 + 16 + lh) * N + col0 + lc);
        __syncthreads();
        *(float4*)(As + lh * 68 + lc)        = a0;
        *(float4*)(As + (16 + lh) * 68 + lc) = a1;
        *(float4*)(Bs + lh * 68 + lc)        = b0;
        *(float4*)(Bs + (16 + lh) * 68 + lc) = b1;
        __syncthreads();
#pragma unroll
        for (int kk = 0; kk < 32; ++kk) {
            const float4 a = *(const float4*)(As + kk * 68 + ty * 4);
            const float4 b = *(const float4*)(Bs + kk * 68 + tx * 4);
            const float ar[4] = {a.x, a.y, a.z, a.w};
            const float br[4] = {b.x, b.y, b.z, b.w};
#pragma unroll
            for (int i = 0; i < 4; ++i)
#pragma unroll
                for (int j = 0; j < 4; ++j)
                    acc[i][j] = fmaf(ar[i], br[j], acc[i][j]);
        }
    }
#pragma unroll
    for (int i = 0; i < 4; ++i) {
        float4 o;
        o.x = acc[i][0]; o.y = acc[i][1]; o.z = acc[i][2]; o.w = acc[i][3];
        *(float4*)(P + (size_t)(ty * 4 + i) * N + col0 + tx * 4) = o;
    }
}

__global__ __launch_bounds__(256) void k_red(
    const float* __restrict__ pH, const float* __restrict__ pX,
    float* __restrict__ M_h, float* __restrict__ M_x)
{
    const int NH4 = 4 * 64 * 1024 / 4;
    const int id = blockIdx.x * 256 + threadIdx.x;
    if (id < NH4) {
        const int per = 64 * 1024 / 4;
        const int g = id / per, r = id % per;
        const float4* b = (const float4*)pH + (size_t)g * 4 * per + r;
        const float4 a0 = b[0], a1 = b[per], a2 = b[2 * per], a3 = b[3 * per];
        float4 o;
        o.x = a0.x + a1.x + a2.x + a3.x; o.y = a0.y + a1.y + a2.y + a3.y;
        o.z = a0.z + a1.z + a2.z + a3.z; o.w = a0.w + a1.w + a2.w + a3.w;
        ((float4*)M_h)[id] = o;
    } else {
        const int id2 = id - NH4;
        const int per = 64 * 512 / 4;
        const int g = id2 / per, r = id2 % per;
        const float4* b = (const float4*)pX + (size_t)g * 4 * per + r;
        const float4 a0 = b[0], a1 = b[per], a2 = b[2 * per], a3 = b[3 * per];
        float4 o;
        o.x = a0.x + a1.x + a2.x + a3.x; o.y = a0.y + a1.y + a2.y + a3.y;
        o.z = a0.z + a1.z + a2.z + a3.z; o.w = a0.w + a1.w + a2.w + a3.w;
        ((float4*)M_x)[id2] = o;
    }
}

// ---------------------------------------------------------------------------
// k_p2: P^T[col][k2] = sum_z zW[g*64+z][k2] * M[g][z][c]  (col = global out col)
// + cbias[col] = sum_z b[g*64+z] * M[g][z][c].  Output: hi/lo planes in the
// standard blocked frag order (B operand of k_out), region-local colblk.
// grid (48, 4): 48 col-chunks of 128 (32 for dhw_h, 16 for dhw_x), 4 k-quarters.
// ---------------------------------------------------------------------------
__global__ __launch_bounds__(256) void k_p2(
    const float* __restrict__ zh_W, const float* __restrict__ zh_b,
    const float* __restrict__ zx_W, const float* __restrict__ zx_b,
    const float* __restrict__ M_h,  const float* __restrict__ M_x,
    u16* __restrict__ phHi, u16* __restrict__ phLo,
    u16* __restrict__ pxHi, u16* __restrict__ pxLo,
    float* __restrict__ cbias)
{
    const int cb  = blockIdx.x;        // 0..47
    const int ks4 = blockIdx.y;        // 0..3
    const bool isH = cb < 32;
    const int g    = isH ? (cb >> 3) : ((cb - 32) >> 2);
    const int N    = isH ? HIDn : INn;
    const int cloc = isH ? ((cb & 7) * 128) : (((cb - 32) & 3) * 128);
    const float* W  = (isH ? zh_W : zx_W) + (size_t)g * 64 * HYPn;  // [64][256]
    const float* bb = (isH ? zh_b : zx_b) + g * 64;
    const float* M  = (isH ? M_h  : M_x ) + (size_t)g * 64 * N + cloc;
    u16* pHi = isH ? phHi : pxHi;
    u16* pLo = isH ? phLo : pxLo;
    const long ubase = (long)(isH ? cb : cb - 32) * 4096;
    const int t = threadIdx.x;

    __shared__ float Ms[128 * 65];     // Ms[c*65+z] = M[z][cloc+c]
    __shared__ float Wsh[64 * 64];     // Wsh[z*64+kk] = W[z][ks4*64+kk]
    for (int i = t; i < 8192; i += 256) {
        const int z = i >> 7, c = i & 127;
        Ms[c * 65 + z] = M[(size_t)z * N + c];
    }
    for (int i = t; i < 4096; i += 256) {
        const int z = i >> 6, kk = i & 63;
        Wsh[z * 64 + kk] = W[(size_t)z * 256 + ks4 * 64 + kk];
    }
    __syncthreads();

    for (int uu = t; uu < 1024; uu += 256) {
        const int kbl  = uu >> 9;                 // 0/1 within quarter
        const int r2   = uu & 511;
        const int lane = r2 & 63;
        const int c    = (r2 >> 6) * 16 + (lane & 15);
        const int kloc = kbl * 32 + (lane >> 4) * 8;
        float p0 = 0.f, p1 = 0.f, p2 = 0.f, p3 = 0.f;
        float p4 = 0.f, p5 = 0.f, p6 = 0.f, p7 = 0.f;
#pragma unroll 8
        for (int z = 0; z < 64; ++z) {
            const float m = Ms[c * 65 + z];
            const float4 w0 = *(const float4*)(Wsh + z * 64 + kloc);
            const float4 w1 = *(const float4*)(Wsh + z * 64 + kloc + 4);
            p0 = fmaf(w0.x, m, p0); p1 = fmaf(w0.y, m, p1);
            p2 = fmaf(w0.z, m, p2); p3 = fmaf(w0.w, m, p3);
            p4 = fmaf(w1.x, m, p4); p5 = fmaf(w1.y, m, p5);
            p6 = fmaf(w1.z, m, p6); p7 = fmaf(w1.w, m, p7);
        }
        const float pv[8] = {p0, p1, p2, p3, p4, p5, p6, p7};
        union { u16 us[8]; uint4 v; } H, L;
#pragma unroll
        for (int j = 0; j < 8; ++j) {
            const u16 h = f2bf(pv[j]);
            H.us[j] = h;
            L.us[j] = f2bf(pv[j] - bf2f(h));
        }
        const long uo = ubase + (long)(ks4 * 2 + kbl) * 512 + r2;
        *(uint4*)(pHi + uo * 8) = H.v;
        *(uint4*)(pLo + uo * 8) = L.v;
    }
    if (ks4 == 0 && t < 128) {
        float a = 0.f;
#pragma unroll 8
        for (int z = 0; z < 64; ++z) a = fmaf(bb[z], Ms[t * 65 + z], a);
        cbias[cb * 128 + t] = a;   // global col = cb*128 + c for both regions
    }
}

// ---------------------------------------------------------------------------
// k_out: [out1|out2|out3] = hn[8192,256] @ [P_h | P_x | zbW^T][256,6400] (+c)
// Single MFMA GEMM, K=256 (8 steps BK=32), 128x128 tiles, grid (64, 50).
// Region: by<32 dhw_h, by<48 dhw_x, else z_b. Same staging/frags as k_ifgo.
// ---------------------------------------------------------------------------
__global__ __launch_bounds__(256) void k_out(
    const u16* __restrict__ hnHi, const u16* __restrict__ hnLo,
    const u16* __restrict__ phHi, const u16* __restrict__ phLo,
    const u16* __restrict__ pxHi, const u16* __restrict__ pxLo,
    const u16* __restrict__ zbHi, const u16* __restrict__ zbLo,
    const float* __restrict__ cbias,
    float* __restrict__ out1, float* __restrict__ out2, float* __restrict__ out3)
{
    __shared__ __align__(16) u16 lds[4 * 4096];
    const int t = threadIdx.x;
    const int w = t >> 6, l = t & 63;
    const int wr = w >> 1, wc = w & 1;
    const int bx = blockIdx.x, by = blockIdx.y;

    const u16 *bH, *bL; long cbB;
    if (by < 32)      { bH = phHi; bL = phLo; cbB = (long)by * 4096; }
    else if (by < 48) { bH = pxHi; bL = pxLo; cbB = (long)(by - 32) * 4096; }
    else              { bH = zbHi; bL = zbLo; cbB = (long)(by - 48) * 4096; }
    const long caB = (long)bx * 4096;

    f32x4 acc[4][4] = {};

    for (int s = 0; s < 8; ++s) {
        const long ca = caB + (long)s * 512;
        const long cb = cbB + (long)s * 512;
        __syncthreads();
#pragma unroll
        for (int i = 0; i < 2; ++i) {
            const int un = i * 256 + t;
            __builtin_amdgcn_global_load_lds(
                (const __attribute__((address_space(1))) u32*)(hnHi + (ca + un) * 8),
                (__attribute__((address_space(3))) u32*)(lds + 0 * 4096 + un * 8), 16, 0, 0);
            __builtin_amdgcn_global_load_lds(
                (const __attribute__((address_space(1))) u32*)(hnLo + (ca + un) * 8),
                (__attribute__((address_space(3))) u32*)(lds + 1 * 4096 + un * 8), 16, 0, 0);
            __builtin_amdgcn_global_load_lds(
                (const __attribute__((address_space(1))) u32*)(bH + (cb + un) * 8),
                (__attribute__((address_space(3))) u32*)(lds + 2 * 4096 + un * 8), 16, 0, 0);
            __builtin_amdgcn_global_load_lds(
                (const __attribute__((address_space(1))) u32*)(bL + (cb + un) * 8),
                (__attribute__((address_space(3))) u32*)(lds + 3 * 4096 + un * 8), 16, 0, 0);
        }
        __syncthreads();

        s16x8 ah[4], al[4], bh[4], bl[4];
#pragma unroll
        for (int f = 0; f < 4; ++f) {
            const int ua = ((wr * 4 + f) * 64 + l) * 8;
            const int ub = ((wc * 4 + f) * 64 + l) * 8;
            ah[f] = *(const s16x8*)(lds + 0 * 4096 + ua);
            al[f] = *(const s16x8*)(lds + 1 * 4096 + ua);
            bh[f] = *(const s16x8*)(lds + 2 * 4096 + ub);
            bl[f] = *(const s16x8*)(lds + 3 * 4096 + ub);
        }
#pragma unroll
        for (int fm = 0; fm < 4; ++fm)
#pragma unroll
            for (int fn = 0; fn < 4; ++fn) {
                acc[fm][fn] = __builtin_amdgcn_mfma_f32_16x16x32_bf16(ah[fm], bh[fn], acc[fm][fn], 0, 0, 0);
                acc[fm][fn] = __builtin_amdgcn_mfma_f32_16x16x32_bf16(ah[fm], bl[fn], acc[fm][fn], 0, 0, 0);
                acc[fm][fn] = __builtin_amdgcn_mfma_f32_16x16x32_bf16(al[fm], bh[fn], acc[fm][fn], 0, 0, 0);
            }
    }

    // Epilogue: C/D col=lane&15, row=(lane>>4)*4+reg; region-decoded store.
    const int row0 = bx * 128 + wr * 64;
    const int colb = by * 128 + wc * 64;
#pragma unroll
    for (int fn = 0; fn < 4; ++fn) {
        const int col = colb + fn * 16 + (l & 15);
        float bias; float* base; int ld2;
        if (col < 4096) {
            bias = cbias[col];
            const int g = col >> 10;
            base = out1 + (size_t)g * Bn * 1024 + (col & 1023);
            ld2 = 1024;
        } else if (col < 6144) {
            bias = cbias[col];
            const int cg = col - 4096;
            const int g = cg >> 9;
            base = out2 + (size_t)g * Bn * 512 + (cg & 511);
            ld2 = 512;
        } else {
            bias = 0.f;
            const int cg = col - 6144;
            const int g = cg >> 6;
            base = out3 + (size_t)g * Bn * 64 + (cg & 63);
            ld2 = 64;
        }
#pragma unroll
        for (int fm = 0; fm < 4; ++fm) {
            const int r0 = row0 + fm * 16 + (l >> 4) * 4;
#pragma unroll
            for (int r = 0; r < 4; ++r)
                base[(size_t)(r0 + r) * ld2] = acc[fm][fn][r] + bias;
        }
    }
}

// ---------------------------------------------------------------------------
extern "C" void kernel_launch(void* const* d_in, const int* in_sizes, int n_in,
                              void* d_out, int out_size, void* d_ws, size_t ws_size,
                              hipStream_t stream)
{
    const float* e        = (const float*)d_in[1];
    const float* h_hat    = (const float*)d_in[4];
    const float* c_hat    = (const float*)d_in[5];
    const float* hyper_Wx = (const float*)d_in[6];
    const float* hyper_Wh = (const float*)d_in[7];
    const float* hyper_b  = (const float*)d_in[8];
    const float* ln_g     = (const float*)d_in[9];
    const float* ln_b     = (const float*)d_in[10];
    const float* lnc_g    = (const float*)d_in[11];
    const float* lnc_b    = (const float*)d_in[12];
    const float* zh_W     = (const float*)d_in[13];
    const float* zh_b     = (const float*)d_in[14];
    const float* zx_W     = (const float*)d_in[15];
    const float* zx_b     = (const float*)d_in[16];
    const float* zb_W     = (const float*)d_in[17];
    const float* dh_W     = (const float*)d_in[18];
    const float* dx_W     = (const float*)d_in[19];
    const float* w_h      = (const float*)d_in[20];
    const float* w_x      = (const float*)d_in[21];

    float* out1 = (float*)d_out;                        // dhw_h [4, B, HID]
    float* out2 = out1 + (size_t)4 * Bn * HIDn;         // dhw_x [4, B, IN]
    float* out3 = out2 + (size_t)4 * Bn * INn;          // z_b^T [4, B, NZ]

    float* ws    = (float*)d_ws;
    float* ifgo  = ws;  ws += (size_t)Bn * 1024;        // 32 MiB
    float* hn    = ws;  ws += (size_t)Bn * HYPn;        //  8 MiB
    float* M_h   = ws;  ws += (size_t)4 * NZn * HIDn;   //  1 MiB
    float* M_x   = ws;  ws += (size_t)4 * NZn * INn;    //  0.5 MiB
    float* pH    = ws;  ws += (size_t)16 * NZn * HIDn;  //  4 MiB
    float* pX    = ws;  ws += (size_t)16 * NZn * INn;   //  2 MiB
    float* cbias = ws;  ws += 6144;                     //  24 KiB
    u16* bp    = (u16*)ws;
    u16* eHi   = bp;  bp += (size_t)Bn * EMBn;
    u16* eLo   = bp;  bp += (size_t)Bn * EMBn;
    u16* hhHi  = bp;  bp += (size_t)Bn * HYPn;
    u16* hhLo  = bp;  bp += (size_t)Bn * HYPn;
    u16* wxHi  = bp;  bp += (size_t)HIDn * EMBn;
    u16* wxLo  = bp;  bp += (size_t)HIDn * EMBn;
    u16* whHi  = bp;  bp += (size_t)HIDn * HYPn;
    u16* whLo  = bp;  bp += (size_t)HIDn * HYPn;
    u16* zbHi  = bp;  bp += (size_t)HYPn * HYPn;
    u16* zbLo  = bp;  bp += (size_t)HYPn * HYPn;
    u16* hnHi  = bp;  bp += (size_t)Bn * HYPn;
    u16* hnLo  = bp;  bp += (size_t)Bn * HYPn;
    u16* phHi  = bp;  bp += (size_t)4096 * HYPn;        // 4096 cols x 256 k
    u16* phLo  = bp;  bp += (size_t)4096 * HYPn;
    u16* pxHi  = bp;  bp += (size_t)2048 * HYPn;
    u16* pxLo  = bp;  /* last */

    // 1. input planes (now incl. zb_W)
    k_prep<<<dim3(3488), 256, 0, stream>>>(e, h_hat, hyper_Wx, hyper_Wh, zb_W,
        eHi, eLo, hhHi, hhLo, wxHi, wxLo, whHi, whLo, zbHi, zbLo);
    // 2. collapsed M = dW^T w, then P = zW^T M (+ bias row) as frag planes
    k_dm_part<<<dim3(16, 4, 8), 256, 0, stream>>>(dh_W, w_h, dx_W, w_x, pH, pX);
    k_red<<<dim3(384), 256, 0, stream>>>(pH, pX, M_h, M_x);
    k_p2<<<dim3(48, 4), 256, 0, stream>>>(zh_W, zh_b, zx_W, zx_b, M_h, M_x,
        phHi, phLo, pxHi, pxLo, cbias);
    // 3. inner cell
    k_ifgo_mfma<<<dim3(64, 8), 256, 0, stream>>>(
        eHi, eLo, hhHi, hhLo, wxHi, wxLo, whHi, whLo, hyper_b, ifgo);
    k_cell<<<dim3(Bn), 256, 0, stream>>>(ifgo, c_hat, ln_g, ln_b, lnc_g, lnc_b, hn);
    k_prep1<<<dim3(1024), 256, 0, stream>>>(hn, hnHi, hnLo);
    // 4. single fused output GEMM (dhw_h | dhw_x | z_b)
    k_out<<<dim3(64, 50), 256, 0, stream>>>(hnHi, hnLo, phHi, phLo, pxHi, pxLo,
        zbHi, zbLo, cbias, out1, out2, out3);
}